// Round 3
// baseline (3588.178 us; speedup 1.0000x reference)
//
#include <hip/hip_runtime.h>

// QRNN: T=512, B=32, D=1024, Q=256.
//  Phase A (prep):  build WhT/UhT fp16 [e][d] (transposed); zero tagged h buffer.
//  Phase B (gemm):  wh_out = x @ Wh + b -> fp32 into d_out (overwritten by scan).
//  Phase C (scan):  h_t = tanh(wh_out[t] + h_{t-1} @ Uh), in-place on d_out.
//   R3 scheme: NO flags, NO fences, NO barriers in the t-loop. h is communicated as
//   self-validating tagged u32 words ((t+1)<<16 | fp16) through the coherent LLC
//   (relaxed agent atomics). Parity double-buffer; dataflow proves no overwrite of
//   unread data. 128 single-wave WGs (2 row groups x 64 col groups of 16).
//   Uh frags in LDS, frag-major layout (conflict-free; R2 had 8.5M bank conflicts).

#define TT 512
#define BB 32
#define DD 1024

typedef _Float16 f16;
typedef _Float16 f16x8 __attribute__((ext_vector_type(8)));
typedef _Float16 f16x4 __attribute__((ext_vector_type(4)));
typedef float f32x4 __attribute__((ext_vector_type(4)));

__device__ __constant__ int   QCOMP[4][4] = {{0,1,2,3},{1,0,3,2},{2,3,0,1},{3,2,1,0}};
__device__ __constant__ float QSIGN[4][4] = {{ 1.f, 1.f, 1.f, 1.f},
                                             {-1.f, 1.f, 1.f,-1.f},
                                             {-1.f,-1.f, 1.f, 1.f},
                                             {-1.f, 1.f,-1.f, 1.f}};

__device__ __forceinline__ float qpick(int cmp, const float* a, const float* b,
                                       const float* c, const float* d, int idx) {
    const float* s = (cmp == 0) ? a : (cmp == 1) ? b : (cmp == 2) ? c : d;
    return s[idx];
}

// ---------------- Phase A -------------------------------------------------------------
__global__ void qrnn_prep(const float* __restrict__ wr, const float* __restrict__ wi,
                          const float* __restrict__ wj, const float* __restrict__ wk,
                          const float* __restrict__ ur, const float* __restrict__ ui,
                          const float* __restrict__ uj, const float* __restrict__ uk,
                          f16* __restrict__ WhT, f16* __restrict__ UhT,
                          unsigned int* __restrict__ hbuf)
{
    int bid = blockIdx.x;
    int gid = bid * 256 + threadIdx.x;
    if (bid < 4096) {                    // WhT: 1M elements, flat = e*1024 + d
        int e = gid >> 10, d = gid & 1023;
        int bc = e >> 8, j = e & 255, br = d >> 8, i = d & 255;
        float v = QSIGN[br][bc] * qpick(QCOMP[br][bc], wr, wi, wj, wk, i * 256 + j);
        WhT[gid] = (f16)v;
    } else if (bid < 8192) {             // UhT
        int g = gid - 4096 * 256;
        int e = g >> 10, d = g & 1023;
        int bc = e >> 8, j = e & 255, br = d >> 8, i = d & 255;
        float v = QSIGN[br][bc] * qpick(QCOMP[br][bc], ur, ui, uj, uk, i * 256 + j);
        UhT[g] = (f16)v;
    } else {                             // hbuf: 2 parity x 32 x 1024 u32 -> tag 0
        int g = gid - 8192 * 256;
        if (g < 65536) hbuf[g] = 0;
    }
}

// ---------------- Phase B: wh_out = x @ Wh + bias ------------------------------------
__global__ __launch_bounds__(256) void qrnn_gemm(const float* __restrict__ x,
                                                 const f16* __restrict__ WhT,
                                                 const float* __restrict__ bias,
                                                 float* __restrict__ out)
{
    __shared__ f16 Ash[128][72];
    __shared__ f16 Bsh[128][72];

    const int tn = blockIdx.x, tm = blockIdx.y;
    const int tid = threadIdx.x;
    const int lane = tid & 63, w = tid >> 6;
    const int wm = (w >> 1) * 64, wn = (w & 1) * 64;
    const int m0 = tm * 128, n0 = tn * 128;
    const int l15 = lane & 15, q8 = (lane >> 4) * 8;

    f32x4 acc[4][4] = {};

    const int arow = tid >> 4;
    const int acol = (tid & 15) * 4;
    const int brow = tid >> 3;
    const int bcol = (tid & 7) * 8;

    for (int kb = 0; kb < DD; kb += 64) {
        #pragma unroll
        for (int p = 0; p < 8; ++p) {
            int rrow = p * 16 + arow;
            float4 v = *(const float4*)(x + (size_t)(m0 + rrow) * DD + kb + acol);
            f16x4 hv = {(f16)v.x, (f16)v.y, (f16)v.z, (f16)v.w};
            *(f16x4*)&Ash[rrow][acol] = hv;
        }
        #pragma unroll
        for (int p = 0; p < 4; ++p) {
            int rn = p * 32 + brow;
            f16x8 v = *(const f16x8*)(WhT + (size_t)(n0 + rn) * DD + kb + bcol);
            *(f16x8*)&Bsh[rn][bcol] = v;
        }
        __syncthreads();
        #pragma unroll
        for (int ks = 0; ks < 64; ks += 32) {
            f16x8 af[4], bf[4];
            #pragma unroll
            for (int i = 0; i < 4; ++i) af[i] = *(const f16x8*)&Ash[wm + i * 16 + l15][ks + q8];
            #pragma unroll
            for (int i = 0; i < 4; ++i) bf[i] = *(const f16x8*)&Bsh[wn + i * 16 + l15][ks + q8];
            #pragma unroll
            for (int i = 0; i < 4; ++i)
                #pragma unroll
                for (int j = 0; j < 4; ++j)
                    acc[i][j] = __builtin_amdgcn_mfma_f32_16x16x32_f16(af[i], bf[j], acc[i][j], 0, 0, 0);
        }
        __syncthreads();
    }
    const int quad = lane >> 4;
    #pragma unroll
    for (int i = 0; i < 4; ++i)
        #pragma unroll
        for (int j = 0; j < 4; ++j) {
            int col = n0 + wn + j * 16 + l15;
            float bz = bias[col];
            #pragma unroll
            for (int rr = 0; rr < 4; ++rr) {
                int row = m0 + wm + i * 16 + quad * 4 + rr;
                out[(size_t)row * DD + col] = acc[i][j][rr] + bz;
            }
        }
}

// ---------------- Phase C: sequential scan, tag-synchronized -------------------------
// WG = 1 wave, 16 cols. hbuf word = ((t+1)<<16) | fp16(h_t).  Parity buffers of
// 32x1024 u32. Consumer at step t polls for tag == t in the (t-1)&1 buffer.
__global__ __launch_bounds__(64, 1) void qrnn_scan(const f16* __restrict__ UhT,
                                                   unsigned int* __restrict__ hbuf,
                                                   float* __restrict__ out)
{
    __shared__ f16 Ush[32 * 64 * 8];   // frag-major: frag(u,lane) at (u*64+lane)*8 halves

    const int r   = blockIdx.x >> 6;        // row group 0..1 (batch rows 16r..16r+15)
    const int c2  = blockIdx.x & 63;        // col group 0..63 (16 cols)
    const int lane = threadIdx.x;
    const int l15 = lane & 15, quad = lane >> 4, q8 = quad * 8;
    const int dcol = c2 * 16 + l15;         // output feature col (D/B-frag n)
    const int brow = r * 16 + quad * 4;     // first output batch row (D-frag)

    // stage Uh frags -> LDS, frag-major (consecutive lanes -> consecutive 16B: no conflicts)
    {
        const f16* src = UhT + (size_t)dcol * DD + q8;
        #pragma unroll
        for (int u = 0; u < 32; ++u)
            *(f16x8*)&Ush[(u * 64 + lane) * 8] = *(const f16x8*)(src + (size_t)u * 32);
    }
    __syncthreads();

    const unsigned int* harow = hbuf + (r * 16 + l15) * 1024 + q8;  // A[m=l15][k=q8+j+32u]
    unsigned int* hwrow = hbuf + brow * 1024 + dcol;

    #pragma unroll 1
    for (int t = 0; t < TT; ++t) {
        const size_t obase = (size_t)t * (BB * DD) + (size_t)brow * DD + dcol;
        float wh[4];
        #pragma unroll
        for (int i = 0; i < 4; ++i) wh[i] = out[obase + (size_t)i * DD];

        f32x4 acc[4] = {{0.f,0.f,0.f,0.f},{0.f,0.f,0.f,0.f},
                        {0.f,0.f,0.f,0.f},{0.f,0.f,0.f,0.f}};
        if (t > 0) {
            const unsigned int* hsrc = harow + ((t - 1) & 1) * 32768;
            const unsigned int tag = (unsigned int)t;          // producer stored (t-1)+1
            const unsigned int tt  = (tag << 16) | tag;

            unsigned long long rawA[32], rawB[32];

            auto loadq = [&](int q, unsigned long long* raw) {
                #pragma unroll
                for (int ii = 0; ii < 8; ++ii) {
                    const unsigned long long* p =
                        (const unsigned long long*)(hsrc + (q * 8 + ii) * 32);
                    #pragma unroll
                    for (int j = 0; j < 4; ++j)
                        raw[ii * 4 + j] = __hip_atomic_load(p + j, __ATOMIC_RELAXED,
                                                            __HIP_MEMORY_SCOPE_AGENT);
                }
            };
            auto useq = [&](int q, const unsigned long long* raw) -> bool {
                unsigned int bad = 0;
                unsigned int d[8][4];
                #pragma unroll
                for (int ii = 0; ii < 8; ++ii) {
                    #pragma unroll
                    for (int j = 0; j < 4; ++j) {
                        unsigned int w0 = (unsigned int)raw[ii * 4 + j];
                        unsigned int w1 = (unsigned int)(raw[ii * 4 + j] >> 32);
                        bad |= __builtin_amdgcn_perm(w1, w0, 0x07060302u) ^ tt;  // tag pair
                        d[ii][j] = __builtin_amdgcn_perm(w1, w0, 0x05040100u);   // fp16 pair
                    }
                }
                if (__any(bad != 0)) return false;
                #pragma unroll
                for (int ii = 0; ii < 8; ++ii) {
                    f16x8 bf = *(const f16x8*)&Ush[((q * 8 + ii) * 64 + lane) * 8];
                    uint4 dv = {d[ii][0], d[ii][1], d[ii][2], d[ii][3]};
                    f16x8 af = __builtin_bit_cast(f16x8, dv);
                    acc[q] = __builtin_amdgcn_mfma_f32_16x16x32_f16(af, bf, acc[q], 0, 0, 0);
                }
                return true;
            };

            loadq(0, rawA);
            loadq(1, rawB);
            #pragma unroll
            for (int q = 0; q < 4; ++q) {
                unsigned long long* cur = (q & 1) ? rawB : rawA;
                while (!useq(q, cur)) loadq(q, cur);
                if (q < 2) loadq(q + 2, cur);   // refill consumed buffer (depth-2 pipeline)
            }
        }
        // epilogue: h = tanh(sum(acc) + wh); fp32 -> d_out; tagged fp16 -> hbuf
        unsigned int* hwp = hwrow + (t & 1) * 32768;
        const unsigned int ntag = ((unsigned int)(t + 1)) << 16;
        #pragma unroll
        for (int i = 0; i < 4; ++i) {
            float z = ((acc[0][i] + acc[1][i]) + (acc[2][i] + acc[3][i])) + wh[i];
            float e = __expf(2.0f * z);
            float hv = 1.0f - 2.0f * __builtin_amdgcn_rcpf(e + 1.0f);
            out[obase + (size_t)i * DD] = hv;
            f16 hh = (f16)hv;
            unsigned int word = (unsigned int)__builtin_bit_cast(unsigned short, hh) | ntag;
            __hip_atomic_store(hwp + i * 1024, word, __ATOMIC_RELAXED,
                               __HIP_MEMORY_SCOPE_AGENT);
        }
    }
}

extern "C" void kernel_launch(void* const* d_in, const int* in_sizes, int n_in,
                              void* d_out, int out_size, void* d_ws, size_t ws_size,
                              hipStream_t stream)
{
    const float* x  = (const float*)d_in[0];
    const float* wr = (const float*)d_in[1];
    const float* wi = (const float*)d_in[2];
    const float* wj = (const float*)d_in[3];
    const float* wk = (const float*)d_in[4];
    const float* ur = (const float*)d_in[5];
    const float* ui = (const float*)d_in[6];
    const float* uj = (const float*)d_in[7];
    const float* uk = (const float*)d_in[8];
    const float* bias = (const float*)d_in[9];
    float* out = (float*)d_out;

    char* ws = (char*)d_ws;
    f16* WhT  = (f16*)(ws);                          // 2 MB
    f16* UhT  = (f16*)(ws + (1 << 21));              // 2 MB
    unsigned int* hbuf = (unsigned int*)(ws + (1 << 22));  // 2 x 128 KB tagged h

    hipLaunchKernelGGL(qrnn_prep, dim3(8448), dim3(256), 0, stream,
                       wr, wi, wj, wk, ur, ui, uj, uk, WhT, UhT, hbuf);
    hipLaunchKernelGGL(qrnn_gemm, dim3(8, 128), dim3(256), 0, stream,
                       x, WhT, bias, out);
    hipLaunchKernelGGL(qrnn_scan, dim3(128), dim3(64), 0, stream,
                       UhT, hbuf, out);
}